// Round 1
// baseline (12.980 us; speedup 1.0000x reference)
//
#include <hip/hip_runtime.h>
#include <stdint.h>

// Problem constants (fixed by setup_inputs)
#define B    8
#define CIN  128
#define H    16
#define W    16
#define COUT 128
// ws layout: [0, 32768)        xbits: B*H*W * 2 u64  (bit c of word c>>6 = sign(x)>0)
//            [32768, 51200)    wbits: COUT*9 * 2 u64

__global__ void pack_signs_kernel(const float* __restrict__ x,
                                  const float* __restrict__ wgt,
                                  unsigned long long* __restrict__ xb,
                                  unsigned long long* __restrict__ wb) {
    const int NX = B * H * W * CIN;   // 262144  (64-aligned)
    const int NW = COUT * 9 * CIN;    // 147456  (64-aligned)
    int tid = blockIdx.x * blockDim.x + threadIdx.x;
    if (tid < NX) {
        int c   = tid & 127;
        int pos = tid >> 7;                 // b*256 + h*16 + w
        int w = pos & 15, h = (pos >> 4) & 15, b = pos >> 8;
        float v = x[((b * CIN + c) * H + h) * W + w];   // NCHW gather
        unsigned long long m = __ballot(v > 0.0f);      // 64 lanes = 64 channels
        if ((threadIdx.x & 63) == 0) xb[pos * 2 + (c >> 6)] = m;
    } else if (tid < NX + NW) {
        int idx = tid - NX;
        int c   = idx & 127;
        int pos = idx >> 7;                 // o*9 + (ky*3+kx)
        float v = wgt[pos * 128 + c];       // (o,ky,kx,c) layout: contiguous c
        unsigned long long m = __ballot(v > 0.0f);
        if ((threadIdx.x & 63) == 0) wb[pos * 2 + (c >> 6)] = m;
    }
}

__global__ __launch_bounds__(256) void maj3_kernel(
        const unsigned long long* __restrict__ xb,
        const unsigned long long* __restrict__ wb,
        float* __restrict__ out) {
    const int bo = blockIdx.x;          // b*COUT + o
    const int o  = bo & 127;
    const int b  = bo >> 7;
    const int h  = threadIdx.x >> 4;
    const int w  = threadIdx.x & 15;

    // Stage this batch-image's packed sign plane (16x16 x 2 u64 = 4 KB)
    __shared__ unsigned long long sx[H * W * 2];
    {
        int i = threadIdx.x;            // 256 threads stage 512 u64 (2 each)
        sx[i * 2]     = xb[(b * 256 + i) * 2];
        sx[i * 2 + 1] = xb[(b * 256 + i) * 2 + 1];
    }
    __syncthreads();

    // Weight sign words for this o — block-uniform address -> scalar loads
    unsigned long long wreg[9][2];
#pragma unroll
    for (int k = 0; k < 9; ++k) {
        wreg[k][0] = wb[(o * 9 + k) * 2];
        wreg[k][1] = wb[(o * 9 + k) * 2 + 1];
    }

    int acc = 0;
#pragma unroll
    for (int ky = 0; ky < 3; ++ky) {
        int ih = h + ky - 1;
        if (ih < 0 || ih >= H) continue;   // whole kernel row padded -> sign(0)=0

        unsigned long long p[3][2];        // XNOR product bits per tap (static idx)
        bool v0 = (w - 1 >= 0);
        bool v2 = (w + 1 < W);
#pragma unroll
        for (int kx = 0; kx < 3; ++kx) {
            int iw = w + kx - 1;
            int iwc = iw < 0 ? 0 : (iw > W - 1 ? W - 1 : iw);   // clamped (masked later)
            int base = (ih * W + iwc) * 2;
            p[kx][0] = ~(sx[base]     ^ wreg[ky * 3 + kx][0]);
            p[kx][1] = ~(sx[base + 1] ^ wreg[ky * 3 + kx][1]);
        }
        if (v0 && v2) {
            // all 3 taps valid: per-channel majority bit
            unsigned long long m0 = (p[0][0] & p[1][0]) | ((p[0][0] | p[1][0]) & p[2][0]);
            unsigned long long m1 = (p[0][1] & p[1][1]) | ((p[0][1] | p[1][1]) & p[2][1]);
            acc += 2 * (__popcll(m0) + __popcll(m1)) - 128;
        } else {
            // exactly one of kx=0 / kx=2 is padding; valid pair = (p1, q)
            unsigned long long q0 = v0 ? p[0][0] : p[2][0];
            unsigned long long q1 = v0 ? p[0][1] : p[2][1];
            // s_c in {-2,0,2}: +1 iff both bits set, -1 iff both clear
            acc += __popcll(p[1][0] & q0) + __popcll(p[1][1] & q1)
                 + __popcll(p[1][0] | q0) + __popcll(p[1][1] | q1) - 128;
        }
    }
    out[((b * COUT + o) * H + h) * W + w] = (float)acc;
}

extern "C" void kernel_launch(void* const* d_in, const int* in_sizes, int n_in,
                              void* d_out, int out_size, void* d_ws, size_t ws_size,
                              hipStream_t stream) {
    const float* x   = (const float*)d_in[0];
    const float* wgt = (const float*)d_in[1];
    float* out = (float*)d_out;

    unsigned long long* xb = (unsigned long long*)d_ws;                       // 32 KB
    unsigned long long* wb = (unsigned long long*)((char*)d_ws + 32768);      // 18 KB

    const int NPACK = B * H * W * CIN + COUT * 9 * CIN;   // 409600 = 1600*256
    pack_signs_kernel<<<NPACK / 256, 256, 0, stream>>>(x, wgt, xb, wb);
    maj3_kernel<<<B * COUT, 256, 0, stream>>>(xb, wb, out);
}

// Round 2
// 10.908 us; speedup vs baseline: 1.1899x; 1.1899x over previous
//
#include <hip/hip_runtime.h>
#include <stdint.h>

// Problem constants (fixed by setup_inputs)
#define B    8
#define CIN  128
#define H    16
#define W    16
#define COUT 128
// Fused single-kernel design:
//   grid = B * (COUT/4) = 256 blocks (one per CU), 512 threads each.
//   Each block handles (b, group of 4 output channels):
//     phase 1a: pack 4*9 weight words via __ballot (lane = channel, coalesced)
//     phase 1b: pack the 16x16x128 sign plane of image b: thread=(word,pos),
//               64-channel loop, each wave reads 64 consecutive pos (coalesced)
//     phase 2:  XNOR + 3-way majority + popcount per (pos, 2 o's)/thread

__global__ __launch_bounds__(512) void maj3_fused_kernel(
        const float* __restrict__ x,
        const float* __restrict__ wgt,
        float* __restrict__ out) {
    const int blk = blockIdx.x;       // b*32 + og
    const int og  = blk & 31;         // o = og*4 + ol, ol in [0,4)
    const int b   = blk >> 5;
    const int t   = threadIdx.x;

    // +1 u64-pair padding per h-row breaks the 256B (bank-wrap) aliasing
    __shared__ unsigned long long sx[16 * 17 * 2];   // [h][w(padded)][word]
    __shared__ unsigned long long sw[4 * 9 * 2];     // [ol][ky*3+kx][word]

    // ---- phase 1a: weight pack (72 words, 8 waves x 9 ballots, coalesced) ----
    {
        const int wave = t >> 6, lane = t & 63;
        #pragma unroll
        for (int j = 0; j < 9; ++j) {
            int i    = wave * 9 + j;          // 0..71 == (ol*9+k)*2+word
            int word = i & 1;
            int k    = (i >> 1) % 9;
            int ol   = (i >> 1) / 9;
            float v = wgt[(((og * 4 + ol) * 9 + k) << 7) + (word << 6) + lane];
            unsigned long long m = __ballot(v > 0.0f);
            if (lane == 0) sw[i] = m;
        }
    }

    // ---- phase 1b: x sign-plane pack (coalesced: wave = 64 consecutive pos) ----
    {
        const int word = t >> 8;              // 0 or 1 (changes at wave boundary)
        const int pos  = t & 255;             // h*16+w
        const float* xp = x + ((b * CIN + (word << 6)) << 8) + pos;
        unsigned long long m = 0;
        #pragma unroll
        for (int j = 0; j < 64; ++j)          // 64 independent strided loads (ILP)
            m |= (unsigned long long)(xp[j << 8] > 0.0f) << j;
        int h = pos >> 4, w = pos & 15;
        sx[(h * 17 + w) * 2 + word] = m;
    }
    __syncthreads();

    // ---- phase 2: compute 2 output channels per thread ----
    const int pos   = t & 255;
    const int opair = t >> 8;                 // 0/1 -> o_locals {2*opair, 2*opair+1}
    const int h = pos >> 4, w = pos & 15;
    const bool v0 = (w > 0), v2 = (w < 15);
    int acc0 = 0, acc1 = 0;

    #pragma unroll
    for (int ky = 0; ky < 3; ++ky) {
        int ih = h + ky - 1;
        if (ih < 0 || ih >= H) continue;      // padded row: sign(0)=0 contribution

        int base = ih * 17 * 2;
        int iwl = v0 ? (w - 1) : w;           // clamped; masked by v0/v2 below
        int iwr = v2 ? (w + 1) : w;
        unsigned long long s00 = sx[base + iwl * 2], s01 = sx[base + iwl * 2 + 1];
        unsigned long long s10 = sx[base + w   * 2], s11 = sx[base + w   * 2 + 1];
        unsigned long long s20 = sx[base + iwr * 2], s21 = sx[base + iwr * 2 + 1];

        #pragma unroll
        for (int oo = 0; oo < 2; ++oo) {
            int ol = opair * 2 + oo;
            const unsigned long long* wk = &sw[(ol * 9 + ky * 3) * 2]; // wave-uniform -> broadcast
            unsigned long long p00 = ~(s00 ^ wk[0]), p01 = ~(s01 ^ wk[1]);
            unsigned long long p10 = ~(s10 ^ wk[2]), p11 = ~(s11 ^ wk[3]);
            unsigned long long p20 = ~(s20 ^ wk[4]), p21 = ~(s21 ^ wk[5]);
            int a;
            if (v0 && v2) {
                // interior: per-channel 3-input majority
                unsigned long long m0 = (p00 & p10) | ((p00 | p10) & p20);
                unsigned long long m1 = (p01 & p11) | ((p01 | p11) & p21);
                a = 2 * (__popcll(m0) + __popcll(m1)) - 128;
            } else {
                // one kx tap padded: s in {-2,0,2} -> (#both1) - (#both0)
                unsigned long long q0 = v0 ? p00 : p20;
                unsigned long long q1 = v0 ? p01 : p21;
                a = __popcll(p10 & q0) + __popcll(p11 & q1)
                  + __popcll(p10 | q0) + __popcll(p11 | q1) - 128;
            }
            if (oo == 0) acc0 += a; else acc1 += a;
        }
    }

    const int o0 = og * 4 + opair * 2;
    out[((b * COUT + o0) << 8) + pos]       = (float)acc0;  // coalesced (pos fast)
    out[((b * COUT + o0 + 1) << 8) + pos]   = (float)acc1;
}

extern "C" void kernel_launch(void* const* d_in, const int* in_sizes, int n_in,
                              void* d_out, int out_size, void* d_ws, size_t ws_size,
                              hipStream_t stream) {
    const float* x   = (const float*)d_in[0];
    const float* wgt = (const float*)d_in[1];
    float* out = (float*)d_out;

    maj3_fused_kernel<<<B * (COUT / 4), 512, 0, stream>>>(x, wgt, out);
}

// Round 3
// 10.663 us; speedup vs baseline: 1.2173x; 1.0230x over previous
//
#include <hip/hip_runtime.h>
#include <stdint.h>

// Problem constants (fixed by setup_inputs)
#define B    8
#define CIN  128
#define H    16
#define W    16
#define COUT 128

typedef unsigned int u32;
typedef unsigned long long u64;

// One fused kernel. grid = B * (COUT/4) = 256 blocks (1/CU), 512 threads.
// Block = (b, group of 4 output channels).
//   1a: pack 4*9 weight sign-words via __ballot (lane = channel; c contiguous -> coalesced)
//   1b: pack image-b sign plane: thread=(16-chan group, pos-quad), 16 float4 loads
//       (each wave load = 1 KB contiguous), u16 halfword writes into u32 LDS tile
//   2 : XNOR + 3-way majority + popcount; uint4 (b128) LDS reads, 2 outputs/thread

__global__ __launch_bounds__(512) void maj3_fused_kernel(
        const float* __restrict__ x,
        const float* __restrict__ wgt,
        float* __restrict__ out) {
    const int blk = blockIdx.x;       // b*32 + og
    const int og  = blk & 31;
    const int b   = blk >> 5;
    const int t   = threadIdx.x;

    // [h][w padded to 17][4 x u32] -> 16 B per pos, b128-aligned, pad breaks row aliasing
    __shared__ u32 sx[16 * 17 * 4];
    __shared__ u32 sw[4 * 9 * 4];     // [ol][k=ky*3+kx][4 x u32]

    // ---- 1a: weight pack (72 u64 ballots, 9 per wave, coalesced reads) ----
    {
        const int wave = t >> 6, lane = t & 63;
        #pragma unroll
        for (int j = 0; j < 9; ++j) {
            int i  = wave * 9 + j;            // (ol*9+k)*2 + wd64
            int wd = i & 1;
            int k  = (i >> 1) % 9;
            int ol = (i >> 1) / 9;
            float v = wgt[(((og * 4 + ol) * 9 + k) << 7) + (wd << 6) + lane];
            u64 m = __ballot(v > 0.0f);
            if (lane == 0) {
                sw[(ol * 9 + k) * 4 + wd * 2]     = (u32)m;
                sw[(ol * 9 + k) * 4 + wd * 2 + 1] = (u32)(m >> 32);
            }
        }
    }

    // ---- 1b: x sign pack, float4 (4 consecutive pos) per load ----
    {
        const int wh = t >> 6;                // 16-channel group: c = wh*16 + j
        const int q  = t & 63;                // pos quad: pos = 4q + e
        const float4* xp = (const float4*)(x + ((b * CIN + wh * 16) << 8)) + q;
        u32 m[4] = {0, 0, 0, 0};
        #pragma unroll
        for (int j = 0; j < 16; ++j) {        // 16 independent 16B coalesced loads
            float4 v = xp[j << 6];            // channel stride = 256 floats = 64 float4
            m[0] |= (u32)(v.x > 0.0f) << j;
            m[1] |= (u32)(v.y > 0.0f) << j;
            m[2] |= (u32)(v.z > 0.0f) << j;
            m[3] |= (u32)(v.w > 0.0f) << j;
        }
        unsigned short* sxh = (unsigned short*)sx;
        #pragma unroll
        for (int e = 0; e < 4; ++e) {         // static indices (unrolled)
            int pos = 4 * q + e;
            int h = pos >> 4, w = pos & 15;
            sxh[(h * 17 + w) * 8 + wh] = (unsigned short)m[e];
        }
    }
    __syncthreads();

    // ---- 2: compute (2 output channels per thread) ----
    const int pos   = t & 255;
    const int opair = t >> 8;
    const int h = pos >> 4, w = pos & 15;
    const bool v0 = (w > 0), v2 = (w < 15);
    int acc0 = 0, acc1 = 0;

    const uint4* sx4 = (const uint4*)sx;
    const uint4* sw4 = (const uint4*)sw;

    #pragma unroll
    for (int ky = 0; ky < 3; ++ky) {
        int ih = h + ky - 1;
        if (ih < 0 || ih >= H) continue;      // fully padded kernel row: sign(0)=0

        int rb = ih * 17;
        uint4 s0 = sx4[rb + (v0 ? w - 1 : w)];   // clamped; masked below
        uint4 s1 = sx4[rb + w];
        uint4 s2 = sx4[rb + (v2 ? w + 1 : w)];

        #pragma unroll
        for (int oo = 0; oo < 2; ++oo) {
            int ol = opair * 2 + oo;
            uint4 w0 = sw4[ol * 9 + ky * 3 + 0];  // wave-uniform -> broadcast
            uint4 w1 = sw4[ol * 9 + ky * 3 + 1];
            uint4 w2 = sw4[ol * 9 + ky * 3 + 2];

            uint4 p0, p1, p2;                 // XNOR product bits (v_xnor_b32)
            p0.x = ~(s0.x ^ w0.x); p0.y = ~(s0.y ^ w0.y);
            p0.z = ~(s0.z ^ w0.z); p0.w = ~(s0.w ^ w0.w);
            p1.x = ~(s1.x ^ w1.x); p1.y = ~(s1.y ^ w1.y);
            p1.z = ~(s1.z ^ w1.z); p1.w = ~(s1.w ^ w1.w);
            p2.x = ~(s2.x ^ w2.x); p2.y = ~(s2.y ^ w2.y);
            p2.z = ~(s2.z ^ w2.z); p2.w = ~(s2.w ^ w2.w);

            int a;
            if (v0 && v2) {
                // interior: per-channel 3-input majority, 2*pop(maj)-128
                u32 mx = (p0.x & p1.x) | ((p0.x | p1.x) & p2.x);
                u32 my = (p0.y & p1.y) | ((p0.y | p1.y) & p2.y);
                u32 mz = (p0.z & p1.z) | ((p0.z | p1.z) & p2.z);
                u32 mw = (p0.w & p1.w) | ((p0.w | p1.w) & p2.w);
                a = 2 * (__popc(mx) + __popc(my) + __popc(mz) + __popc(mw)) - 128;
            } else {
                // one kx tap padded; pop(p&q)+pop(p|q) == pop(p)+pop(q)
                u32 qx = v0 ? p0.x : p2.x, qy = v0 ? p0.y : p2.y;
                u32 qz = v0 ? p0.z : p2.z, qw = v0 ? p0.w : p2.w;
                a = __popc(p1.x) + __popc(p1.y) + __popc(p1.z) + __popc(p1.w)
                  + __popc(qx) + __popc(qy) + __popc(qz) + __popc(qw) - 128;
            }
            if (oo == 0) acc0 += a; else acc1 += a;
        }
    }

    const int o0 = og * 4 + opair * 2;
    out[((b * COUT + o0) << 8) + pos]     = (float)acc0;   // pos-fast: coalesced
    out[((b * COUT + o0 + 1) << 8) + pos] = (float)acc1;
}

extern "C" void kernel_launch(void* const* d_in, const int* in_sizes, int n_in,
                              void* d_out, int out_size, void* d_ws, size_t ws_size,
                              hipStream_t stream) {
    const float* x   = (const float*)d_in[0];
    const float* wgt = (const float*)d_in[1];
    float* out = (float*)d_out;

    maj3_fused_kernel<<<B * (COUT / 4), 512, 0, stream>>>(x, wgt, out);
}

// Round 4
// 10.622 us; speedup vs baseline: 1.2220x; 1.0039x over previous
//
#include <hip/hip_runtime.h>
#include <stdint.h>

// Problem constants (fixed by setup_inputs)
#define B    8
#define CIN  128
#define H    16
#define W    16
#define COUT 128

typedef unsigned int u32;
typedef unsigned long long u64;

// One fused kernel. grid = B * (COUT/4) = 256 blocks (1/CU), 512 threads.
// Sign-convention: we pack the NEGATIVE bit (sign bit) for both x and w.
// XNOR-majority is invariant when both operand bit conventions flip, so the
// compute phase is identical. (No exact-0.0 values in the data — verified by
// absmax==0 under the previous >0 convention.)
//   0 : issue 16 float4 x-loads into registers (latency hidden under 1a)
//   1a: pack 4*9 weight sign-words via __ballot(v<0) (lane = channel, coalesced)
//   1b: build x sign words from registers: 2 VALU/bit (lshr + lshl_or)
//   2 : XNOR + 3-way majority + popcount; uint4 (b128) LDS reads, 2 outs/thread

__global__ __launch_bounds__(512) void maj3_fused_kernel(
        const float* __restrict__ x,
        const float* __restrict__ wgt,
        float* __restrict__ out) {
    const int blk = blockIdx.x;       // b*32 + og
    const int og  = blk & 31;
    const int b   = blk >> 5;
    const int t   = threadIdx.x;

    // [h][w padded to 17][4 x u32]: 16 B/pos, b128-aligned, pad breaks row aliasing
    __shared__ u32 sx[16 * 17 * 4];
    __shared__ u32 sw[4 * 9 * 4];     // [ol][k=ky*3+kx][4 x u32]

    // ---- phase 0: issue x loads early (16 independent 16B coalesced loads) ----
    const int wh = t >> 6;                    // 16-channel group: c = wh*16 + j
    const int q  = t & 63;                    // pos quad: pos = 4q + e
    const float4* xp = (const float4*)(x + ((b * CIN + wh * 16) << 8)) + q;
    float4 xv[16];
    #pragma unroll
    for (int j = 0; j < 16; ++j)
        xv[j] = xp[j << 6];                   // channel stride = 64 float4

    // ---- phase 1a: weight pack (72 u64 ballots, 9 per wave, coalesced) ----
    {
        const int lane = t & 63;
        #pragma unroll
        for (int j = 0; j < 9; ++j) {
            int i  = wh * 9 + j;              // (ol*9+k)*2 + wd64
            int wd = i & 1;
            int k  = (i >> 1) % 9;
            int ol = (i >> 1) / 9;
            float v = wgt[(((og * 4 + ol) * 9 + k) << 7) + (wd << 6) + lane];
            u64 m = __ballot(v < 0.0f);       // negative-bit pack
            if (lane == 0) {
                sw[(ol * 9 + k) * 4 + wd * 2]     = (u32)m;
                sw[(ol * 9 + k) * 4 + wd * 2 + 1] = (u32)(m >> 32);
            }
        }
    }

    // ---- phase 1b: build sign words (2 VALU/bit), write u16 halves to LDS ----
    {
        u32 m0 = 0, m1 = 0, m2 = 0, m3 = 0;
        #pragma unroll
        for (int j = 0; j < 16; ++j) {
            m0 |= (__float_as_uint(xv[j].x) >> 31) << j;   // v_lshrrev + v_lshl_or
            m1 |= (__float_as_uint(xv[j].y) >> 31) << j;
            m2 |= (__float_as_uint(xv[j].z) >> 31) << j;
            m3 |= (__float_as_uint(xv[j].w) >> 31) << j;
        }
        unsigned short* sxh = (unsigned short*)sx;
        int p0 = 4 * q;                        // pos = p0 + e
        int h0 = p0 >> 4, w0 = p0 & 15;        // quad stays within one h-row (w0%4==0)
        int base = (h0 * 17 + w0) * 8 + wh;
        sxh[base]      = (unsigned short)m0;
        sxh[base + 8]  = (unsigned short)m1;
        sxh[base + 16] = (unsigned short)m2;
        sxh[base + 24] = (unsigned short)m3;
    }
    __syncthreads();

    // ---- phase 2: compute (2 output channels per thread) ----
    const int pos   = t & 255;
    const int opair = t >> 8;
    const int h = pos >> 4, w = pos & 15;
    const bool v0 = (w > 0), v2 = (w < 15);
    int acc0 = 0, acc1 = 0;

    const uint4* sx4 = (const uint4*)sx;
    const uint4* sw4 = (const uint4*)sw;

    #pragma unroll
    for (int ky = 0; ky < 3; ++ky) {
        int ih = h + ky - 1;
        if (ih < 0 || ih >= H) continue;      // fully padded kernel row: sign(0)=0

        int rb = ih * 17;
        uint4 s0 = sx4[rb + (v0 ? w - 1 : w)];   // clamped; masked below
        uint4 s1 = sx4[rb + w];
        uint4 s2 = sx4[rb + (v2 ? w + 1 : w)];

        #pragma unroll
        for (int oo = 0; oo < 2; ++oo) {
            int ol = opair * 2 + oo;
            uint4 w0v = sw4[ol * 9 + ky * 3 + 0];  // wave-uniform -> broadcast
            uint4 w1v = sw4[ol * 9 + ky * 3 + 1];
            uint4 w2v = sw4[ol * 9 + ky * 3 + 2];

            uint4 p0, p1, p2;                 // product-positive bits (v_xnor_b32)
            p0.x = ~(s0.x ^ w0v.x); p0.y = ~(s0.y ^ w0v.y);
            p0.z = ~(s0.z ^ w0v.z); p0.w = ~(s0.w ^ w0v.w);
            p1.x = ~(s1.x ^ w1v.x); p1.y = ~(s1.y ^ w1v.y);
            p1.z = ~(s1.z ^ w1v.z); p1.w = ~(s1.w ^ w1v.w);
            p2.x = ~(s2.x ^ w2v.x); p2.y = ~(s2.y ^ w2v.y);
            p2.z = ~(s2.z ^ w2v.z); p2.w = ~(s2.w ^ w2v.w);

            int a;
            if (v0 && v2) {
                // interior: per-channel 3-input majority, 2*pop(maj)-128
                u32 mx = (p0.x & p1.x) | ((p0.x | p1.x) & p2.x);
                u32 my = (p0.y & p1.y) | ((p0.y | p1.y) & p2.y);
                u32 mz = (p0.z & p1.z) | ((p0.z | p1.z) & p2.z);
                u32 mw = (p0.w & p1.w) | ((p0.w | p1.w) & p2.w);
                a = 2 * (__popc(mx) + __popc(my) + __popc(mz) + __popc(mw)) - 128;
            } else {
                // one kx tap padded; pop(p&q)+pop(p|q) == pop(p)+pop(q)
                u32 qx = v0 ? p0.x : p2.x, qy = v0 ? p0.y : p2.y;
                u32 qz = v0 ? p0.z : p2.z, qw = v0 ? p0.w : p2.w;
                a = __popc(p1.x) + __popc(p1.y) + __popc(p1.z) + __popc(p1.w)
                  + __popc(qx) + __popc(qy) + __popc(qz) + __popc(qw) - 128;
            }
            if (oo == 0) acc0 += a; else acc1 += a;
        }
    }

    const int o0 = og * 4 + opair * 2;
    out[((b * COUT + o0) << 8) + pos]     = (float)acc0;   // pos-fast: coalesced
    out[((b * COUT + o0 + 1) << 8) + pos] = (float)acc1;
}

extern "C" void kernel_launch(void* const* d_in, const int* in_sizes, int n_in,
                              void* d_out, int out_size, void* d_ws, size_t ws_size,
                              hipStream_t stream) {
    const float* x   = (const float*)d_in[0];
    const float* wgt = (const float*)d_in[1];
    float* out = (float*)d_out;

    maj3_fused_kernel<<<B * (COUT / 4), 512, 0, stream>>>(x, wgt, out);
}